// Round 1
// 344.325 us; speedup vs baseline: 1.1178x; 1.1178x over previous
//
#include <hip/hip_runtime.h>

typedef unsigned short u16;
typedef short v8s __attribute__((ext_vector_type(8)));
typedef float v4f __attribute__((ext_vector_type(4)));
typedef unsigned int v4u __attribute__((ext_vector_type(4)));

#define BB 4
#define LL 2048
#define DD 1024
#define NH 16
#define HD 64
// 0.125 (1/sqrt(64)) * log2(e): puts attention logits in exp2 domain
#define QSCALE 0.18033688011112042f
#define PAD 72  // LDS pad for attn K/V tiles

__device__ __forceinline__ float bf2f(u16 u) {
  union { unsigned int i; float f; } v; v.i = ((unsigned int)u) << 16; return v.f;
}
__device__ __forceinline__ u16 f2bf(float f) {
  union { float f; unsigned int i; } v; v.f = f;
  unsigned int u = v.i;
  return (u16)((u + 0x7fffu + ((u >> 16) & 1u)) >> 16);
}
// async global->LDS, 16B/lane. LDS dest = wave-uniform base + lane*16.
__device__ __forceinline__ void gl_lds16(const u16* g, u16* l) {
  __builtin_amdgcn_global_load_lds(
      (const __attribute__((address_space(1))) void*)g,
      (__attribute__((address_space(3))) void*)l, 16, 0, 0);
}
// pack two f32 -> one u32 of 2x bf16 (RNE); no builtin on gfx950
__device__ __forceinline__ unsigned cvtpk_bf16(float lo, float hi) {
  unsigned r;
  asm("v_cvt_pk_bf16_f32 %0, %1, %2" : "=v"(r) : "v"(lo), "v"(hi));
  return r;
}
// a' = {a.r0, a.r1, b.r0, b.r1}; b' = {a.r2, a.r3, b.r2, b.r3} (rows = 16-lane groups)
__device__ __forceinline__ void pl32swap(unsigned& a, unsigned& b) {
  asm("v_permlane32_swap_b32 %0, %1" : "+v"(a), "+v"(b));
}
// a' = {a.r0, b.r0, a.r2, b.r2}; b' = {a.r1, b.r1, a.r3, b.r3}
__device__ __forceinline__ void pl16swap(unsigned& a, unsigned& b) {
  asm("v_permlane16_swap_b32 %0, %1" : "+v"(a), "+v"(b));
}

// ---------------- sentinel fill (contract-violation signal), fp32 ----------------
__global__ __launch_bounds__(256) void fill_val(float* __restrict__ out, float v, int n) {
  int i = blockIdx.x * 256 + threadIdx.x;
  if (i < n) out[i] = v;
}

// ---------------- cast x fp32 -> bf16 --------------------------------------------
__global__ __launch_bounds__(256) void cast_x(
    const float* __restrict__ x, u16* __restrict__ Xb) {
  int i = (blockIdx.x * 256 + threadIdx.x) * 8;
  float4 a = *(const float4*)(x + i);
  float4 b = *(const float4*)(x + i + 4);
  v8s v;
  v[0] = (short)f2bf(a.x); v[1] = (short)f2bf(a.y);
  v[2] = (short)f2bf(a.z); v[3] = (short)f2bf(a.w);
  v[4] = (short)f2bf(b.x); v[5] = (short)f2bf(b.y);
  v[6] = (short)f2bf(b.z); v[7] = (short)f2bf(b.w);
  *(v8s*)(Xb + i) = v;
}

// ---------------- weight transpose: W[k][n] fp32 -> WT[n][k] bf16, 4 mats --------
__global__ __launch_bounds__(256) void transpose_w(
    const float* __restrict__ Wq, const float* __restrict__ Wk,
    const float* __restrict__ Wv, const float* __restrict__ Wo,
    u16* __restrict__ WT) {
  __shared__ u16 tile[64][72];
  int z = blockIdx.z;
  const float* src = (z == 0) ? Wq : (z == 1) ? Wk : (z == 2) ? Wv : Wo;
  u16* dst = WT + (size_t)z * DD * DD;
  int n0 = blockIdx.x * 64, k0 = blockIdx.y * 64;
  int tid = threadIdx.x;
#pragma unroll
  for (int i = 0; i < 2; ++i) {
    int cid = i * 256 + tid;
    int r = cid >> 3, c = (cid & 7) * 8;
    const float* sp = src + (size_t)(k0 + r) * DD + n0 + c;
    float4 a = *(const float4*)sp;
    float4 b = *(const float4*)(sp + 4);
    tile[r][c + 0] = f2bf(a.x); tile[r][c + 1] = f2bf(a.y);
    tile[r][c + 2] = f2bf(a.z); tile[r][c + 3] = f2bf(a.w);
    tile[r][c + 4] = f2bf(b.x); tile[r][c + 5] = f2bf(b.y);
    tile[r][c + 6] = f2bf(b.z); tile[r][c + 7] = f2bf(b.w);
  }
  __syncthreads();
#pragma unroll
  for (int i = 0; i < 2; ++i) {
    int cid = i * 256 + tid;
    int r = cid >> 3, c = (cid & 7) * 8;
    v8s v;
#pragma unroll
    for (int j = 0; j < 8; ++j) v[j] = (short)tile[c + j][r];
    *(v8s*)(dst + (size_t)(n0 + r) * DD + k0 + c) = v;
  }
}

// ---------------- 128x128 GEMM, global_load_lds staging (m97 structure) ----------
// Fused N: bx = blockIdx.x + nbase in [0,32): mode = bx>>3 (1024 cols/mode).
// mode 0: Xb @ WqT (scaled) -> Qb[b,h,l,d]     mode 1: -> Kb[b,h,l,d]
// mode 2: Xb @ WvT -> Vtb[b,h,d,l]             mode 3: ctx @ WoT + bo -> projb
__global__ __launch_bounds__(256) void gemm128(
    const u16* __restrict__ Xb, const u16* __restrict__ CTX,
    const u16* __restrict__ WT,
    const float* __restrict__ bq, const float* __restrict__ bk,
    const float* __restrict__ bv, const float* __restrict__ bo,
    u16* __restrict__ Qb, u16* __restrict__ Kb, u16* __restrict__ Vtb,
    u16* __restrict__ projb, int nbase) {
  __shared__ __align__(16) u16 As[128 * 64];  // [m][k], no pad (async-copy contract)
  __shared__ __align__(16) u16 Bs[128 * 64];  // [n][k]

  int tid = threadIdx.x;
  int wave = tid >> 6, lane = tid & 63, quad = lane >> 4, l15 = lane & 15;
  int wr = wave >> 1, wc = wave & 1;  // 2x2 wave grid, 64x64 each
  int bx = blockIdx.x + nbase;
  int mode = bx >> 3;
  int n0g = bx * 128;
  int m0 = blockIdx.y * 128;
  const float* bias = (mode == 0) ? bq : (mode == 1) ? bk : (mode == 2) ? bv : bo;

  const u16* Ab = ((mode == 3) ? CTX : Xb) + (size_t)m0 * DD;
  const u16* Bb = WT + (size_t)n0g * DD;
  // per-lane source offset within a segment: row lane>>3, col (lane&7)*8
  int lrow = lane >> 3, lcol = (lane & 7) * 8;

  v4f acc[4][4] = {};

  for (int kt = 0; kt < DD / 64; ++kt) {
    int k0 = kt * 64;
    __syncthreads();  // prev-iter LDS reads drained
#pragma unroll
    for (int j = 0; j < 4; ++j) {
      int seg = wave * 4 + j;  // 16 segments of 8 rows
      gl_lds16(Ab + (size_t)(seg * 8 + lrow) * DD + k0 + lcol, &As[seg * 512]);
      gl_lds16(Bb + (size_t)(seg * 8 + lrow) * DD + k0 + lcol, &Bs[seg * 512]);
    }
    __syncthreads();  // staging complete (vmcnt drained by barrier)

#pragma unroll
    for (int cc = 0; cc < 2; ++cc) {
      v8s a[4], b[4];
#pragma unroll
      for (int i = 0; i < 4; ++i)
        a[i] = *(const v8s*)&As[(wr * 64 + i * 16 + l15) * 64 + cc * 32 + quad * 8];
#pragma unroll
      for (int j = 0; j < 4; ++j)
        b[j] = *(const v8s*)&Bs[(wc * 64 + j * 16 + l15) * 64 + cc * 32 + quad * 8];
#pragma unroll
      for (int i = 0; i < 4; ++i)
#pragma unroll
        for (int j = 0; j < 4; ++j)
          acc[i][j] = __builtin_amdgcn_mfma_f32_16x16x32_bf16(a[i], b[j], acc[i][j], 0, 0, 0);
    }
  }

#pragma unroll
  for (int j = 0; j < 4; ++j) {
    int n_g = n0g + wc * 64 + j * 16 + l15;
    int n = n_g & (DD - 1);
    float bias_v = bias[n];
#pragma unroll
    for (int i = 0; i < 4; ++i)
#pragma unroll
      for (int r = 0; r < 4; ++r) {
        int m = m0 + wr * 64 + i * 16 + quad * 4 + r;
        float v = acc[i][j][r] + bias_v;
        if (mode == 3) {
          projb[(size_t)m * DD + n] = f2bf(v);
        } else {
          int b = m >> 11, l = m & (LL - 1);
          int h = n >> 6, d = n & 63;
          if (mode == 0) {
            Qb[((size_t)(b * NH + h) * LL + l) * HD + d] = f2bf(v * QSCALE);
          } else if (mode == 1) {
            Kb[((size_t)(b * NH + h) * LL + l) * HD + d] = f2bf(v);
          } else {
            Vtb[((size_t)(b * NH + h) * HD + d) * LL + l] = f2bf(v);
          }
        }
      }
  }
}

// ---------------- flash attention, fixed-max softmax, in-register P --------------
// p = exp2(s-64) is exact softmax (logits |s| << 64); no online max/rescale.
// Swapped QK^T: mfma(K, Q) -> lane holds P[q = lane&15][k = 16t + 4*quad + r],
// i.e. each lane owns a full slice of ITS OWN q-row. Softmax is lane-local;
// P->bf16 via v_cvt_pk_bf16_f32, PV A-fragment assembled in-register with
// permlane32_swap + permlane16_swap (no LDS round-trip for P at all).
// 128 queries per block: 4 waves x 2 strips of 16.
__global__ __launch_bounds__(256, 4) void attn(
    const u16* __restrict__ Qb, const u16* __restrict__ Kb,
    const u16* __restrict__ Vtb, u16* __restrict__ ctx) {
  __shared__ __align__(16) u16 Ks[64 * PAD];       // [key][d]
  __shared__ __align__(16) u16 Vs[64 * PAD];       // [d][key]

  int tid = threadIdx.x;
  int wave = tid >> 6, lane = tid & 63, quad = lane >> 4, l15 = lane & 15;
  int bh = blockIdx.y;
  int q0 = blockIdx.x * 128;

  // Q rows as B-fragments: B[col=q=l15][d = quad*8 + i] (+32 for second half)
  v8s aq[2][2];
#pragma unroll
  for (int s2 = 0; s2 < 2; ++s2) {
    const u16* Qp = Qb + ((size_t)bh * LL + q0 + s2 * 64 + wave * 16 + l15) * HD;
    aq[s2][0] = *(const v8s*)(Qp + quad * 8);
    aq[s2][1] = *(const v8s*)(Qp + 32 + quad * 8);
  }

  v4f o[2][4] = {};
  float ls2[2] = {0.f, 0.f};  // per-strip row-sum for q = l15 (partial over quads)

  const u16* Kbase = Kb + (size_t)bh * LL * HD;
  const u16* Vbase = Vtb + (size_t)bh * HD * LL;

  for (int kt = 0; kt < LL / 64; ++kt) {
    int k0 = kt * 64;
    __syncthreads();
#pragma unroll
    for (int i = 0; i < 2; ++i) {
      int cid = i * 256 + tid;
      int r = cid >> 3, c = (cid & 7) * 8;
      *(v8s*)&Ks[r * PAD + c] = *(const v8s*)(Kbase + (size_t)(k0 + r) * HD + c);
      *(v8s*)&Vs[r * PAD + c] = *(const v8s*)(Vbase + (size_t)r * LL + k0 + c);
    }
    __syncthreads();

    // K rows as A-fragments: A[row=key=l15 (+16t)][d = quad*8 + i]
    v8s ak[4][2];
#pragma unroll
    for (int t = 0; t < 4; ++t) {
      ak[t][0] = *(const v8s*)&Ks[(t * 16 + l15) * PAD + quad * 8];
      ak[t][1] = *(const v8s*)&Ks[(t * 16 + l15) * PAD + 32 + quad * 8];
    }

    v8s ap[2][2];  // [s2][key-chunk c]: PV A-fragments, assembled in-register
#pragma unroll
    for (int s2 = 0; s2 < 2; ++s2) {
      // s[t][r] = S[q=l15][k = 16t + 4*quad + r]
      v4f s[4];
#pragma unroll
      for (int t = 0; t < 4; ++t) {
        v4f z = {};
        z = __builtin_amdgcn_mfma_f32_16x16x32_bf16(ak[t][0], aq[s2][0], z, 0, 0, 0);
        s[t] = __builtin_amdgcn_mfma_f32_16x16x32_bf16(ak[t][1], aq[s2][1], s[t] = z, 0, 0, 0);
      }
      unsigned W[4][2];  // W[t][j] = bf16 pair, k = 16t + 4*quad + {2j, 2j+1}
      float psum = 0.f;
#pragma unroll
      for (int t = 0; t < 4; ++t) {
        float p0 = __builtin_amdgcn_exp2f(s[t][0] - 64.f);
        float p1 = __builtin_amdgcn_exp2f(s[t][1] - 64.f);
        float p2 = __builtin_amdgcn_exp2f(s[t][2] - 64.f);
        float p3 = __builtin_amdgcn_exp2f(s[t][3] - 64.f);
        psum += (p0 + p1) + (p2 + p3);
        W[t][0] = cvtpk_bf16(p0, p1);
        W[t][1] = cvtpk_bf16(p2, p3);
      }
      ls2[s2] += psum;
      // Assemble A-frag words: for chunk c (keys 32c..32c+31), target word w at
      // quad qd must hold k = 32c + 8*qd + {2w, 2w+1}. Derivation (verified):
      //   permlane32_swap(W[2c][j], W[2c+1][j]) -> a = {W0.q0,W0.q1,W1.q0,W1.q1},
      //                                            b = {W0.q2,W0.q3,W1.q2,W1.q3}
      //   permlane16_swap(a, b)                 -> a = {W0.q0,W0.q2,W1.q0,W1.q2} = word j
      //                                            b = {W0.q1,W0.q3,W1.q1,W1.q3} = word 2+j
      union { v4u u; v8s s8; } c0, c1;
#pragma unroll
      for (int j = 0; j < 2; ++j) {
        unsigned a = W[0][j], b = W[1][j];
        pl32swap(a, b); pl16swap(a, b);
        c0.u[j] = a; c0.u[2 + j] = b;
        unsigned a2 = W[2][j], b2 = W[3][j];
        pl32swap(a2, b2); pl16swap(a2, b2);
        c1.u[j] = a2; c1.u[2 + j] = b2;
      }
      ap[s2][0] = c0.s8; ap[s2][1] = c1.s8;
    }

    // PV: V read once per d-tile, shared by both q-strips
#pragma unroll
    for (int t = 0; t < 4; ++t) {
      v8s vb0 = *(const v8s*)&Vs[(t * 16 + l15) * PAD + quad * 8];
      v8s vb1 = *(const v8s*)&Vs[(t * 16 + l15) * PAD + 32 + quad * 8];
#pragma unroll
      for (int s2 = 0; s2 < 2; ++s2) {
        o[s2][t] = __builtin_amdgcn_mfma_f32_16x16x32_bf16(ap[s2][0], vb0, o[s2][t], 0, 0, 0);
        o[s2][t] = __builtin_amdgcn_mfma_f32_16x16x32_bf16(ap[s2][1], vb1, o[s2][t], 0, 0, 0);
      }
    }
  }

  int b = bh >> 4, h = bh & 15;
#pragma unroll
  for (int s2 = 0; s2 < 2; ++s2) {
    float tot = ls2[s2];
    tot += __shfl_xor(tot, 16);
    tot += __shfl_xor(tot, 32);   // all quads: total for q = l15
    float recip = 1.f / tot;
#pragma unroll
    for (int r = 0; r < 4; ++r) {
      float inv = __shfl(recip, quad * 4 + r);  // total for q = quad*4 + r
      int l = q0 + s2 * 64 + wave * 16 + quad * 4 + r;
#pragma unroll
      for (int t = 0; t < 4; ++t)
        ctx[((size_t)(b * LL + l)) * DD + h * HD + t * 16 + l15] =
            f2bf(o[s2][t][r] * inv);
    }
  }
}

// ---------------- residual + LayerNorm -> fp32 output ----------------------------
__global__ __launch_bounds__(256) void resid_ln(
    const float* __restrict__ x, const u16* __restrict__ projb,
    const float* __restrict__ gamma, const float* __restrict__ beta,
    float* __restrict__ out) {
  int row = blockIdx.x, tid = threadIdx.x;
  int base = tid * 4;
  float4 xv = *(const float4*)(x + (size_t)row * DD + base);
  ushort4 pv = *(const ushort4*)(projb + (size_t)row * DD + base);
  float y0 = xv.x + bf2f(pv.x), y1 = xv.y + bf2f(pv.y);
  float y2 = xv.z + bf2f(pv.z), y3 = xv.w + bf2f(pv.w);

  float s = y0 + y1 + y2 + y3;
  s += __shfl_xor(s, 1);  s += __shfl_xor(s, 2);  s += __shfl_xor(s, 4);
  s += __shfl_xor(s, 8);  s += __shfl_xor(s, 16); s += __shfl_xor(s, 32);
  __shared__ float red[8];
  int wv = tid >> 6, ln = tid & 63;
  if (ln == 0) red[wv] = s;
  __syncthreads();
  float mu = (red[0] + red[1] + red[2] + red[3]) * (1.f / DD);

  float d0 = y0 - mu, d1 = y1 - mu, d2 = y2 - mu, d3 = y3 - mu;
  float vv = d0 * d0 + d1 * d1 + d2 * d2 + d3 * d3;
  vv += __shfl_xor(vv, 1);  vv += __shfl_xor(vv, 2);  vv += __shfl_xor(vv, 4);
  vv += __shfl_xor(vv, 8);  vv += __shfl_xor(vv, 16); vv += __shfl_xor(vv, 32);
  if (ln == 0) red[4 + wv] = vv;
  __syncthreads();
  float var = (red[4] + red[5] + red[6] + red[7]) * (1.f / DD);
  float rstd = rsqrtf(var + 1e-5f);

  float4 gv = *(const float4*)(gamma + base);
  float4 bv = *(const float4*)(beta + base);
  float4 ov;
  ov.x = d0 * rstd * gv.x + bv.x;
  ov.y = d1 * rstd * gv.y + bv.y;
  ov.z = d2 * rstd * gv.z + bv.z;
  ov.w = d3 * rstd * gv.w + bv.w;
  *(float4*)(out + (size_t)row * DD + base) = ov;
}

extern "C" void kernel_launch(void* const* d_in, const int* in_sizes, int n_in,
                              void* d_out, int out_size, void* d_ws, size_t ws_size,
                              hipStream_t stream) {
  (void)ws_size;
  float* out = (float*)d_out;

  bool ok = (n_in == 11) && (out_size == BB * LL * DD);
  if (ok) {
    const int want[11] = {BB * LL * DD, DD * DD, DD, DD * DD, DD, DD * DD,
                          DD, DD * DD, DD, DD, DD};
    for (int i = 0; i < 11; ++i) ok = ok && (in_sizes[i] == want[i]);
  }
  if (!ok) {
    fill_val<<<(out_size + 255) / 256, 256, 0, stream>>>(out, 1000.0f, out_size);
    return;
  }

  const float* x     = (const float*)d_in[0];
  const float* Wq    = (const float*)d_in[1];
  const float* bq    = (const float*)d_in[2];
  const float* Wk    = (const float*)d_in[3];
  const float* bk    = (const float*)d_in[4];
  const float* Wv    = (const float*)d_in[5];
  const float* bv    = (const float*)d_in[6];
  const float* Wo    = (const float*)d_in[7];
  const float* bo    = (const float*)d_in[8];
  const float* gamma = (const float*)d_in[9];
  const float* beta  = (const float*)d_in[10];

  // ws: WT 8MB | Xb 16 | Qb 16 | Kb 16 | Vtb 16  (72MB)
  // ctx staged as bf16 in d_out (fp32 buffer, fully rewritten by resid_ln);
  // projb aliases Xb (Xb only feeds QKV GEMM, dead once attn inputs exist).
  char* ws = (char*)d_ws;
  u16* WT   = (u16*)(ws);
  u16* Xb   = (u16*)(ws + (size_t)8 * 1024 * 1024);
  u16* Qb   = (u16*)(ws + (size_t)24 * 1024 * 1024);
  u16* Kb   = (u16*)(ws + (size_t)40 * 1024 * 1024);
  u16* Vtb  = (u16*)(ws + (size_t)56 * 1024 * 1024);
  u16* ctxO = (u16*)d_out;
  u16* projb = Xb;  // Xb dead after QKV GEMM

  cast_x<<<4096, 256, 0, stream>>>(x, Xb);
  transpose_w<<<dim3(16, 16, 4), 256, 0, stream>>>(Wq, Wk, Wv, Wo, WT);
  // fused QKV: N=3072 (24 n-blocks), M=8192 (64 m-blocks)
  gemm128<<<dim3(24, 64), 256, 0, stream>>>(Xb, ctxO, WT, bq, bk, bv, bo,
                                            Qb, Kb, Vtb, projb, 0);
  attn<<<dim3(LL / 128, BB * NH), 256, 0, stream>>>(Qb, Kb, Vtb, ctxO);
  // O-proj: mode 3 (nbase 24), N=1024 (8 n-blocks)
  gemm128<<<dim3(8, 64), 256, 0, stream>>>(Xb, ctxO, WT, bq, bk, bv, bo,
                                           Qb, Kb, Vtb, projb, 24);
  resid_ln<<<8192, 256, 0, stream>>>(x, projb, gamma, beta, out);
}

// Round 2
// 312.117 us; speedup vs baseline: 1.2332x; 1.1032x over previous
//
#include <hip/hip_runtime.h>

typedef unsigned short u16;
typedef short v8s __attribute__((ext_vector_type(8)));
typedef float v4f __attribute__((ext_vector_type(4)));
typedef unsigned int v4u __attribute__((ext_vector_type(4)));

#define BB 4
#define LL 2048
#define DD 1024
#define NH 16
#define HD 64
// 0.125 (1/sqrt(64)) * log2(e): puts attention logits in exp2 domain
#define QSCALE 0.18033688011112042f
#define PAD 72  // LDS pad for attn K/V tiles and gemm epilogue C-tiles

__device__ __forceinline__ float bf2f(u16 u) {
  union { unsigned int i; float f; } v; v.i = ((unsigned int)u) << 16; return v.f;
}
__device__ __forceinline__ u16 f2bf(float f) {
  union { float f; unsigned int i; } v; v.f = f;
  unsigned int u = v.i;
  return (u16)((u + 0x7fffu + ((u >> 16) & 1u)) >> 16);
}
// async global->LDS, 16B/lane. LDS dest = wave-uniform base + lane*16.
__device__ __forceinline__ void gl_lds16(const u16* g, u16* l) {
  __builtin_amdgcn_global_load_lds(
      (const __attribute__((address_space(1))) void*)g,
      (__attribute__((address_space(3))) void*)l, 16, 0, 0);
}
// pack two f32 -> one u32 of 2x bf16 (RNE); no builtin on gfx950
__device__ __forceinline__ unsigned cvtpk_bf16(float lo, float hi) {
  unsigned r;
  asm("v_cvt_pk_bf16_f32 %0, %1, %2" : "=v"(r) : "v"(lo), "v"(hi));
  return r;
}
// a' = {a.r0, a.r1, b.r0, b.r1}; b' = {a.r2, a.r3, b.r2, b.r3} (rows = 16-lane groups)
__device__ __forceinline__ void pl32swap(unsigned& a, unsigned& b) {
  asm("v_permlane32_swap_b32 %0, %1" : "+v"(a), "+v"(b));
}
// a' = {a.r0, b.r0, a.r2, b.r2}; b' = {a.r1, b.r1, a.r3, b.r3}
__device__ __forceinline__ void pl16swap(unsigned& a, unsigned& b) {
  asm("v_permlane16_swap_b32 %0, %1" : "+v"(a), "+v"(b));
}

// ---------------- sentinel fill (contract-violation signal), fp32 ----------------
__global__ __launch_bounds__(256) void fill_val(float* __restrict__ out, float v, int n) {
  int i = blockIdx.x * 256 + threadIdx.x;
  if (i < n) out[i] = v;
}

// ---------------- cast x fp32 -> bf16 --------------------------------------------
__global__ __launch_bounds__(256) void cast_x(
    const float* __restrict__ x, u16* __restrict__ Xb) {
  int i = (blockIdx.x * 256 + threadIdx.x) * 8;
  float4 a = *(const float4*)(x + i);
  float4 b = *(const float4*)(x + i + 4);
  v8s v;
  v[0] = (short)f2bf(a.x); v[1] = (short)f2bf(a.y);
  v[2] = (short)f2bf(a.z); v[3] = (short)f2bf(a.w);
  v[4] = (short)f2bf(b.x); v[5] = (short)f2bf(b.y);
  v[6] = (short)f2bf(b.z); v[7] = (short)f2bf(b.w);
  *(v8s*)(Xb + i) = v;
}

// ---------------- weight transpose: W[k][n] fp32 -> WT[n][k] bf16, 4 mats --------
__global__ __launch_bounds__(256) void transpose_w(
    const float* __restrict__ Wq, const float* __restrict__ Wk,
    const float* __restrict__ Wv, const float* __restrict__ Wo,
    u16* __restrict__ WT) {
  __shared__ u16 tile[64][72];
  int z = blockIdx.z;
  const float* src = (z == 0) ? Wq : (z == 1) ? Wk : (z == 2) ? Wv : Wo;
  u16* dst = WT + (size_t)z * DD * DD;
  int n0 = blockIdx.x * 64, k0 = blockIdx.y * 64;
  int tid = threadIdx.x;
#pragma unroll
  for (int i = 0; i < 2; ++i) {
    int cid = i * 256 + tid;
    int r = cid >> 3, c = (cid & 7) * 8;
    const float* sp = src + (size_t)(k0 + r) * DD + n0 + c;
    float4 a = *(const float4*)sp;
    float4 b = *(const float4*)(sp + 4);
    tile[r][c + 0] = f2bf(a.x); tile[r][c + 1] = f2bf(a.y);
    tile[r][c + 2] = f2bf(a.z); tile[r][c + 3] = f2bf(a.w);
    tile[r][c + 4] = f2bf(b.x); tile[r][c + 5] = f2bf(b.y);
    tile[r][c + 6] = f2bf(b.z); tile[r][c + 7] = f2bf(b.w);
  }
  __syncthreads();
#pragma unroll
  for (int i = 0; i < 2; ++i) {
    int cid = i * 256 + tid;
    int r = cid >> 3, c = (cid & 7) * 8;
    v8s v;
#pragma unroll
    for (int j = 0; j < 8; ++j) v[j] = (short)tile[c + j][r];
    *(v8s*)(dst + (size_t)(n0 + r) * DD + k0 + c) = v;
  }
}

// ---------------- 128x128 GEMM, global_load_lds staging (m97 structure) ----------
// Fused N: bx = n-block + nbase in [0,32): mode = bx>>3 (1024 cols/mode).
// mode 0: Xb @ WqT (scaled) -> Qb[b,h,l,d]     mode 1: -> Kb[b,h,l,d]
// mode 2: Xb @ WvT -> Vtb[b,h,d,l]             mode 3: ctx @ WoT + bo -> projb
// Epilogue: per-wave 64x64 C-tile staged in LDS (reusing As/Bs space) so all
// global stores are coalesced v8s rows instead of 64 scattered 2B stores.
__global__ __launch_bounds__(256) void gemm128(
    const u16* __restrict__ Xb, const u16* __restrict__ CTX,
    const u16* __restrict__ WT,
    const float* __restrict__ bq, const float* __restrict__ bk,
    const float* __restrict__ bv, const float* __restrict__ bo,
    u16* __restrict__ Qb, u16* __restrict__ Kb, u16* __restrict__ Vtb,
    u16* __restrict__ projb, int nbase) {
  // staging (As 16KB + Bs 16KB) and epilogue C-tiles (4 x 64 x 72 x 2B = 36KB) share
  __shared__ __align__(16) u16 LDSU[4 * 64 * PAD];
  u16* As = LDSU;             // [m][k], no pad (async-copy contract)
  u16* Bs = LDSU + 128 * 64;  // [n][k]

  int tid = threadIdx.x;
  int wave = tid >> 6, lane = tid & 63, quad = lane >> 4, l15 = lane & 15;
  int wr = wave >> 1, wc = wave & 1;  // 2x2 wave grid, 64x64 each

  // T1: XCD-aware remap (8 XCDs; grid totals are %8==0 so the remap is bijective).
  // XCD k gets a contiguous chunk of logical ids: bx varies fastest -> blocks on
  // one XCD share the A-panel (m-row), keeping it resident in that XCD's L2.
  int nxg = gridDim.x;
  int orig = blockIdx.y * nxg + blockIdx.x;
  int cpx = (nxg << 6) >> 3;  // nwg/8, nwg = nxg*64
  int id = (orig & 7) * cpx + (orig >> 3);
  int bx = id % nxg + nbase;
  int m0 = (id / nxg) * 128;

  int mode = bx >> 3;
  int n0g = bx * 128;
  const float* bias = (mode == 0) ? bq : (mode == 1) ? bk : (mode == 2) ? bv : bo;

  const u16* Ab = ((mode == 3) ? CTX : Xb) + (size_t)m0 * DD;
  const u16* Bb = WT + (size_t)n0g * DD;
  // per-lane source offset within a segment: row lane>>3, col (lane&7)*8
  int lrow = lane >> 3, lcol = (lane & 7) * 8;

  v4f acc[4][4] = {};

  for (int kt = 0; kt < DD / 64; ++kt) {
    int k0 = kt * 64;
    __syncthreads();  // prev-iter LDS reads drained
#pragma unroll
    for (int j = 0; j < 4; ++j) {
      int seg = wave * 4 + j;  // 16 segments of 8 rows
      gl_lds16(Ab + (size_t)(seg * 8 + lrow) * DD + k0 + lcol, &As[seg * 512]);
      gl_lds16(Bb + (size_t)(seg * 8 + lrow) * DD + k0 + lcol, &Bs[seg * 512]);
    }
    __syncthreads();  // staging complete (vmcnt drained by barrier)

#pragma unroll
    for (int cc = 0; cc < 2; ++cc) {
      v8s a[4], b[4];
#pragma unroll
      for (int i = 0; i < 4; ++i)
        a[i] = *(const v8s*)&As[(wr * 64 + i * 16 + l15) * 64 + cc * 32 + quad * 8];
#pragma unroll
      for (int j = 0; j < 4; ++j)
        b[j] = *(const v8s*)&Bs[(wc * 64 + j * 16 + l15) * 64 + cc * 32 + quad * 8];
#pragma unroll
      for (int i = 0; i < 4; ++i)
#pragma unroll
        for (int j = 0; j < 4; ++j)
          acc[i][j] = __builtin_amdgcn_mfma_f32_16x16x32_bf16(a[i], b[j], acc[i][j], 0, 0, 0);
    }
  }

  // ---- epilogue: stage C-tile in LDS, store coalesced ----
  __syncthreads();  // all waves done reading As/Bs; safe to overwrite
  u16* ct = LDSU + wave * (64 * PAD);  // per-wave 64x64 tile, pad 72
  int rn = lane >> 3, rk = lane & 7;

  if (mode == 2) {
    // ct[n'][m']: thread's 4 acc values are consecutive m -> ushort4 writes
#pragma unroll
    for (int j = 0; j < 4; ++j) {
      int np = j * 16 + l15;
      float bias_v = bias[(n0g + wc * 64 + np) & (DD - 1)];
#pragma unroll
      for (int i = 0; i < 4; ++i) {
        ushort4 p;
        p.x = f2bf(acc[i][j][0] + bias_v);
        p.y = f2bf(acc[i][j][1] + bias_v);
        p.z = f2bf(acc[i][j][2] + bias_v);
        p.w = f2bf(acc[i][j][3] + bias_v);
        *(ushort4*)&ct[np * PAD + i * 16 + quad * 4] = p;
      }
    }
    // rows of Vt (fixed d): contiguous in l. 8 rows x 128B per iteration.
    int b = (m0 + wr * 64) >> 11;
    int lb = (m0 + wr * 64) & (LL - 1);
#pragma unroll
    for (int g = 0; g < 8; ++g) {
      int np = g * 8 + rn;
      int n = (n0g + wc * 64 + np) & (DD - 1);
      int h = n >> 6, d = n & 63;
      v8s v = *(const v8s*)&ct[np * PAD + rk * 8];
      *(v8s*)&Vtb[((size_t)(b * NH + h) * HD + d) * LL + lb + rk * 8] = v;
    }
  } else {
    // ct[m'][n']: scalar b16 writes (2-way bank alias = free), b128 row reads
#pragma unroll
    for (int j = 0; j < 4; ++j) {
      int np = j * 16 + l15;
      float bias_v = bias[(n0g + wc * 64 + np) & (DD - 1)];
#pragma unroll
      for (int i = 0; i < 4; ++i)
#pragma unroll
        for (int r = 0; r < 4; ++r) {
          float v = acc[i][j][r] + bias_v;
          if (mode == 0) v *= QSCALE;
          ct[(i * 16 + quad * 4 + r) * PAD + np] = f2bf(v);
        }
    }
    int nb = (n0g + wc * 64) & (DD - 1);  // 64-aligned
    int h = nb >> 6;
    u16* qk = (mode == 0) ? Qb : Kb;
#pragma unroll
    for (int g = 0; g < 8; ++g) {
      int mp = g * 8 + rn;
      int m_g = m0 + wr * 64 + mp;
      v8s v = *(const v8s*)&ct[mp * PAD + rk * 8];
      if (mode == 3) {
        *(v8s*)&projb[(size_t)m_g * DD + nb + rk * 8] = v;
      } else {
        int b = m_g >> 11, l = m_g & (LL - 1);
        *(v8s*)&qk[((size_t)(b * NH + h) * LL + l) * HD + rk * 8] = v;
      }
    }
  }
}

// ---------------- flash attention, fixed-max softmax, in-register P --------------
// p = exp2(s-64) is exact softmax (logits |s| << 64); no online max/rescale.
// Swapped QK^T: mfma(K, Q) -> lane holds P[q = lane&15][k = 16t + 4*quad + r].
// Softmax lane-local; P->bf16 via v_cvt_pk_bf16_f32, PV A-fragment assembled
// in-register with permlane32_swap + permlane16_swap (no LDS round-trip for P).
// 128 queries per block: 4 waves x 2 strips of 16.
__global__ __launch_bounds__(256, 4) void attn(
    const u16* __restrict__ Qb, const u16* __restrict__ Kb,
    const u16* __restrict__ Vtb, u16* __restrict__ ctx) {
  __shared__ __align__(16) u16 Ks[64 * PAD];       // [key][d]
  __shared__ __align__(16) u16 Vs[64 * PAD];       // [d][key]

  int tid = threadIdx.x;
  int wave = tid >> 6, lane = tid & 63, quad = lane >> 4, l15 = lane & 15;

  // T1: XCD remap — each XCD gets 8 heads x 16 q-tiles; K/V (4MB) fits its L2.
  int orig = blockIdx.y * gridDim.x + blockIdx.x;
  int cpx = (gridDim.x * gridDim.y) >> 3;
  int id = (orig & 7) * cpx + (orig >> 3);
  int q0 = (id & (gridDim.x - 1)) * 128;  // gridDim.x = 16 (pow2)
  int bh = id / gridDim.x;

  // Q rows as B-fragments: B[col=q=l15][d = quad*8 + i] (+32 for second half)
  v8s aq[2][2];
#pragma unroll
  for (int s2 = 0; s2 < 2; ++s2) {
    const u16* Qp = Qb + ((size_t)bh * LL + q0 + s2 * 64 + wave * 16 + l15) * HD;
    aq[s2][0] = *(const v8s*)(Qp + quad * 8);
    aq[s2][1] = *(const v8s*)(Qp + 32 + quad * 8);
  }

  v4f o[2][4] = {};
  float ls2[2] = {0.f, 0.f};  // per-strip row-sum for q = l15 (partial over quads)

  const u16* Kbase = Kb + (size_t)bh * LL * HD;
  const u16* Vbase = Vtb + (size_t)bh * HD * LL;

  for (int kt = 0; kt < LL / 64; ++kt) {
    int k0 = kt * 64;
    __syncthreads();
#pragma unroll
    for (int i = 0; i < 2; ++i) {
      int cid = i * 256 + tid;
      int r = cid >> 3, c = (cid & 7) * 8;
      *(v8s*)&Ks[r * PAD + c] = *(const v8s*)(Kbase + (size_t)(k0 + r) * HD + c);
      *(v8s*)&Vs[r * PAD + c] = *(const v8s*)(Vbase + (size_t)r * LL + k0 + c);
    }
    __syncthreads();

    // K rows as A-fragments: A[row=key=l15 (+16t)][d = quad*8 + i]
    v8s ak[4][2];
#pragma unroll
    for (int t = 0; t < 4; ++t) {
      ak[t][0] = *(const v8s*)&Ks[(t * 16 + l15) * PAD + quad * 8];
      ak[t][1] = *(const v8s*)&Ks[(t * 16 + l15) * PAD + 32 + quad * 8];
    }

    v8s ap[2][2];  // [s2][key-chunk c]: PV A-fragments, assembled in-register
#pragma unroll
    for (int s2 = 0; s2 < 2; ++s2) {
      // s[t][r] = S[q=l15][k = 16t + 4*quad + r]
      v4f s[4];
#pragma unroll
      for (int t = 0; t < 4; ++t) {
        v4f z = {};
        z = __builtin_amdgcn_mfma_f32_16x16x32_bf16(ak[t][0], aq[s2][0], z, 0, 0, 0);
        s[t] = __builtin_amdgcn_mfma_f32_16x16x32_bf16(ak[t][1], aq[s2][1], z, 0, 0, 0);
      }
      unsigned W[4][2];  // W[t][j] = bf16 pair, k = 16t + 4*quad + {2j, 2j+1}
      float psum = 0.f;
#pragma unroll
      for (int t = 0; t < 4; ++t) {
        float p0 = __builtin_amdgcn_exp2f(s[t][0] - 64.f);
        float p1 = __builtin_amdgcn_exp2f(s[t][1] - 64.f);
        float p2 = __builtin_amdgcn_exp2f(s[t][2] - 64.f);
        float p3 = __builtin_amdgcn_exp2f(s[t][3] - 64.f);
        psum += (p0 + p1) + (p2 + p3);
        W[t][0] = cvtpk_bf16(p0, p1);
        W[t][1] = cvtpk_bf16(p2, p3);
      }
      ls2[s2] += psum;
      // Assemble A-frag words: for chunk c (keys 32c..32c+31), target word w at
      // quad qd must hold k = 32c + 8*qd + {2w, 2w+1}:
      //   permlane32_swap(W[2c][j], W[2c+1][j]) -> a = {W0.q0,W0.q1,W1.q0,W1.q1},
      //                                            b = {W0.q2,W0.q3,W1.q2,W1.q3}
      //   permlane16_swap(a, b)                 -> a = word j, b = word 2+j
      union { v4u u; v8s s8; } c0, c1;
#pragma unroll
      for (int j = 0; j < 2; ++j) {
        unsigned a = W[0][j], b = W[1][j];
        pl32swap(a, b); pl16swap(a, b);
        c0.u[j] = a; c0.u[2 + j] = b;
        unsigned a2 = W[2][j], b2 = W[3][j];
        pl32swap(a2, b2); pl16swap(a2, b2);
        c1.u[j] = a2; c1.u[2 + j] = b2;
      }
      ap[s2][0] = c0.s8; ap[s2][1] = c1.s8;
    }

    // PV: V read once per d-tile, shared by both q-strips
#pragma unroll
    for (int t = 0; t < 4; ++t) {
      v8s vb0 = *(const v8s*)&Vs[(t * 16 + l15) * PAD + quad * 8];
      v8s vb1 = *(const v8s*)&Vs[(t * 16 + l15) * PAD + 32 + quad * 8];
#pragma unroll
      for (int s2 = 0; s2 < 2; ++s2) {
        o[s2][t] = __builtin_amdgcn_mfma_f32_16x16x32_bf16(ap[s2][0], vb0, o[s2][t], 0, 0, 0);
        o[s2][t] = __builtin_amdgcn_mfma_f32_16x16x32_bf16(ap[s2][1], vb1, o[s2][t], 0, 0, 0);
      }
    }
  }

  int b = bh >> 4, h = bh & 15;
#pragma unroll
  for (int s2 = 0; s2 < 2; ++s2) {
    float tot = ls2[s2];
    tot += __shfl_xor(tot, 16);
    tot += __shfl_xor(tot, 32);   // all quads: total for q = l15
    float recip = 1.f / tot;
#pragma unroll
    for (int r = 0; r < 4; ++r) {
      float inv = __shfl(recip, quad * 4 + r);  // total for q = quad*4 + r
      int l = q0 + s2 * 64 + wave * 16 + quad * 4 + r;
#pragma unroll
      for (int t = 0; t < 4; ++t)
        ctx[((size_t)(b * LL + l)) * DD + h * HD + t * 16 + l15] =
            f2bf(o[s2][t][r] * inv);
    }
  }
}

// ---------------- residual + LayerNorm -> fp32 output ----------------------------
__global__ __launch_bounds__(256) void resid_ln(
    const float* __restrict__ x, const u16* __restrict__ projb,
    const float* __restrict__ gamma, const float* __restrict__ beta,
    float* __restrict__ out) {
  int row = blockIdx.x, tid = threadIdx.x;
  int base = tid * 4;
  float4 xv = *(const float4*)(x + (size_t)row * DD + base);
  ushort4 pv = *(const ushort4*)(projb + (size_t)row * DD + base);
  float y0 = xv.x + bf2f(pv.x), y1 = xv.y + bf2f(pv.y);
  float y2 = xv.z + bf2f(pv.z), y3 = xv.w + bf2f(pv.w);

  float s = y0 + y1 + y2 + y3;
  s += __shfl_xor(s, 1);  s += __shfl_xor(s, 2);  s += __shfl_xor(s, 4);
  s += __shfl_xor(s, 8);  s += __shfl_xor(s, 16); s += __shfl_xor(s, 32);
  __shared__ float red[8];
  int wv = tid >> 6, ln = tid & 63;
  if (ln == 0) red[wv] = s;
  __syncthreads();
  float mu = (red[0] + red[1] + red[2] + red[3]) * (1.f / DD);

  float d0 = y0 - mu, d1 = y1 - mu, d2 = y2 - mu, d3 = y3 - mu;
  float vv = d0 * d0 + d1 * d1 + d2 * d2 + d3 * d3;
  vv += __shfl_xor(vv, 1);  vv += __shfl_xor(vv, 2);  vv += __shfl_xor(vv, 4);
  vv += __shfl_xor(vv, 8);  vv += __shfl_xor(vv, 16); vv += __shfl_xor(vv, 32);
  if (ln == 0) red[4 + wv] = vv;
  __syncthreads();
  float var = (red[4] + red[5] + red[6] + red[7]) * (1.f / DD);
  float rstd = rsqrtf(var + 1e-5f);

  float4 gv = *(const float4*)(gamma + base);
  float4 bv = *(const float4*)(beta + base);
  float4 ov;
  ov.x = d0 * rstd * gv.x + bv.x;
  ov.y = d1 * rstd * gv.y + bv.y;
  ov.z = d2 * rstd * gv.z + bv.z;
  ov.w = d3 * rstd * gv.w + bv.w;
  *(float4*)(out + (size_t)row * DD + base) = ov;
}

extern "C" void kernel_launch(void* const* d_in, const int* in_sizes, int n_in,
                              void* d_out, int out_size, void* d_ws, size_t ws_size,
                              hipStream_t stream) {
  (void)ws_size;
  float* out = (float*)d_out;

  bool ok = (n_in == 11) && (out_size == BB * LL * DD);
  if (ok) {
    const int want[11] = {BB * LL * DD, DD * DD, DD, DD * DD, DD, DD * DD,
                          DD, DD * DD, DD, DD, DD};
    for (int i = 0; i < 11; ++i) ok = ok && (in_sizes[i] == want[i]);
  }
  if (!ok) {
    fill_val<<<(out_size + 255) / 256, 256, 0, stream>>>(out, 1000.0f, out_size);
    return;
  }

  const float* x     = (const float*)d_in[0];
  const float* Wq    = (const float*)d_in[1];
  const float* bq    = (const float*)d_in[2];
  const float* Wk    = (const float*)d_in[3];
  const float* bk    = (const float*)d_in[4];
  const float* Wv    = (const float*)d_in[5];
  const float* bv    = (const float*)d_in[6];
  const float* Wo    = (const float*)d_in[7];
  const float* bo    = (const float*)d_in[8];
  const float* gamma = (const float*)d_in[9];
  const float* beta  = (const float*)d_in[10];

  // ws: WT 8MB | Xb 16 | Qb 16 | Kb 16 | Vtb 16  (72MB)
  // ctx staged as bf16 in d_out (fp32 buffer, fully rewritten by resid_ln);
  // projb aliases Xb (Xb only feeds QKV GEMM, dead once attn inputs exist).
  char* ws = (char*)d_ws;
  u16* WT   = (u16*)(ws);
  u16* Xb   = (u16*)(ws + (size_t)8 * 1024 * 1024);
  u16* Qb   = (u16*)(ws + (size_t)24 * 1024 * 1024);
  u16* Kb   = (u16*)(ws + (size_t)40 * 1024 * 1024);
  u16* Vtb  = (u16*)(ws + (size_t)56 * 1024 * 1024);
  u16* ctxO = (u16*)d_out;
  u16* projb = Xb;  // Xb dead after QKV GEMM

  cast_x<<<4096, 256, 0, stream>>>(x, Xb);
  transpose_w<<<dim3(16, 16, 4), 256, 0, stream>>>(Wq, Wk, Wv, Wo, WT);
  // fused QKV: N=3072 (24 n-blocks), M=8192 (64 m-blocks)
  gemm128<<<dim3(24, 64), 256, 0, stream>>>(Xb, ctxO, WT, bq, bk, bv, bo,
                                            Qb, Kb, Vtb, projb, 0);
  attn<<<dim3(LL / 128, BB * NH), 256, 0, stream>>>(Qb, Kb, Vtb, ctxO);
  // O-proj: mode 3 (nbase 24), N=1024 (8 n-blocks)
  gemm128<<<dim3(8, 64), 256, 0, stream>>>(Xb, ctxO, WT, bq, bk, bv, bo,
                                           Qb, Kb, Vtb, projb, 24);
  resid_ln<<<8192, 256, 0, stream>>>(x, projb, gamma, beta, out);
}

// Round 3
// 307.988 us; speedup vs baseline: 1.2497x; 1.0134x over previous
//
#include <hip/hip_runtime.h>

typedef unsigned short u16;
typedef short v8s __attribute__((ext_vector_type(8)));
typedef float v4f __attribute__((ext_vector_type(4)));
typedef unsigned int v4u __attribute__((ext_vector_type(4)));

#define BB 4
#define LL 2048
#define DD 1024
#define NH 16
#define HD 64
// 0.125 (1/sqrt(64)) * log2(e): puts attention logits in exp2 domain
#define QSCALE 0.18033688011112042f
#define PAD 72  // LDS pad for attn K/V tiles

__device__ __forceinline__ float bf2f(u16 u) {
  union { unsigned int i; float f; } v; v.i = ((unsigned int)u) << 16; return v.f;
}
__device__ __forceinline__ u16 f2bf(float f) {
  union { float f; unsigned int i; } v; v.f = f;
  unsigned int u = v.i;
  return (u16)((u + 0x7fffu + ((u >> 16) & 1u)) >> 16);
}
// async global->LDS, 16B/lane. LDS dest = wave-uniform base + lane*16.
__device__ __forceinline__ void gl_lds16(const u16* g, u16* l) {
  __builtin_amdgcn_global_load_lds(
      (const __attribute__((address_space(1))) void*)g,
      (__attribute__((address_space(3))) void*)l, 16, 0, 0);
}
// pack two f32 -> one u32 of 2x bf16 (RNE); no builtin on gfx950
__device__ __forceinline__ unsigned cvtpk_bf16(float lo, float hi) {
  unsigned r;
  asm("v_cvt_pk_bf16_f32 %0, %1, %2" : "=v"(r) : "v"(lo), "v"(hi));
  return r;
}
__device__ __forceinline__ void pl32swap(unsigned& a, unsigned& b) {
  asm("v_permlane32_swap_b32 %0, %1" : "+v"(a), "+v"(b));
}
__device__ __forceinline__ void pl16swap(unsigned& a, unsigned& b) {
  asm("v_permlane16_swap_b32 %0, %1" : "+v"(a), "+v"(b));
}

#define MFMA16(a, b, c) __builtin_amdgcn_mfma_f32_16x16x32_bf16((a), (b), (c), 0, 0, 0)
#define VMCNT(n) asm volatile("s_waitcnt vmcnt(" #n ")" ::: "memory")
#define SBAR() __builtin_amdgcn_s_barrier()

// ---------------- sentinel fill (contract-violation signal), fp32 ----------------
__global__ __launch_bounds__(256) void fill_val(float* __restrict__ out, float v, int n) {
  int i = blockIdx.x * 256 + threadIdx.x;
  if (i < n) out[i] = v;
}

// ---------------- cast x fp32 -> bf16 --------------------------------------------
__global__ __launch_bounds__(256) void cast_x(
    const float* __restrict__ x, u16* __restrict__ Xb) {
  int i = (blockIdx.x * 256 + threadIdx.x) * 8;
  float4 a = *(const float4*)(x + i);
  float4 b = *(const float4*)(x + i + 4);
  v8s v;
  v[0] = (short)f2bf(a.x); v[1] = (short)f2bf(a.y);
  v[2] = (short)f2bf(a.z); v[3] = (short)f2bf(a.w);
  v[4] = (short)f2bf(b.x); v[5] = (short)f2bf(b.y);
  v[6] = (short)f2bf(b.z); v[7] = (short)f2bf(b.w);
  *(v8s*)(Xb + i) = v;
}

// ---------------- weight transpose: W[k][n] fp32 -> WT[n][k] bf16, 4 mats --------
__global__ __launch_bounds__(256) void transpose_w(
    const float* __restrict__ Wq, const float* __restrict__ Wk,
    const float* __restrict__ Wv, const float* __restrict__ Wo,
    u16* __restrict__ WT) {
  __shared__ u16 tile[64][72];
  int z = blockIdx.z;
  const float* src = (z == 0) ? Wq : (z == 1) ? Wk : (z == 2) ? Wv : Wo;
  u16* dst = WT + (size_t)z * DD * DD;
  int n0 = blockIdx.x * 64, k0 = blockIdx.y * 64;
  int tid = threadIdx.x;
#pragma unroll
  for (int i = 0; i < 2; ++i) {
    int cid = i * 256 + tid;
    int r = cid >> 3, c = (cid & 7) * 8;
    const float* sp = src + (size_t)(k0 + r) * DD + n0 + c;
    float4 a = *(const float4*)sp;
    float4 b = *(const float4*)(sp + 4);
    tile[r][c + 0] = f2bf(a.x); tile[r][c + 1] = f2bf(a.y);
    tile[r][c + 2] = f2bf(a.z); tile[r][c + 3] = f2bf(a.w);
    tile[r][c + 4] = f2bf(b.x); tile[r][c + 5] = f2bf(b.y);
    tile[r][c + 6] = f2bf(b.z); tile[r][c + 7] = f2bf(b.w);
  }
  __syncthreads();
#pragma unroll
  for (int i = 0; i < 2; ++i) {
    int cid = i * 256 + tid;
    int r = cid >> 3, c = (cid & 7) * 8;
    v8s v;
#pragma unroll
    for (int j = 0; j < 8; ++j) v[j] = (short)tile[c + j][r];
    *(v8s*)(dst + (size_t)(n0 + r) * DD + k0 + c) = v;
  }
}

// ---------------- 256x256 GEMM, 4-phase counted-vmcnt pipeline (T3+T4+T5+T2) -----
// 8 waves (2M x 4N), per-wave 128x64 output. BK=64, double-buffered LDS (128KB).
// Stage unit = 64 rows x 64 k = 8KB = one gl_lds16 issue per wave (1KB each).
// Issue schedule per K-tile t (targets tile t+1): P1: A0,A2  P2: B0,B1
// P3: B2,B3  P4: A1,A3.  Waits: vmcnt(4) at P2-end (A1,A3 of cur land before
// P3 reads), vmcnt(2) at P4-end (A0,A2,B0..B3 of next land before its P1).
// LDS K-loop swizzle: 16B chunk c at row r stored at slot c^(r&7); source
// pre-swizzled (linear gl_lds dest), reads apply same XOR (rule #21).
// Modes by n-block bx (256 cols each): 0-3 Q, 4-7 K, 8-11 V(->Vt), 12-15 O-proj.
__global__ __launch_bounds__(512, 2) void gemm256(
    const u16* __restrict__ Xb, const u16* __restrict__ CTX,
    const u16* __restrict__ WT,
    const float* __restrict__ bq, const float* __restrict__ bk,
    const float* __restrict__ bv, const float* __restrict__ bo,
    u16* __restrict__ Qb, u16* __restrict__ Kb, u16* __restrict__ Vtb,
    u16* __restrict__ projb, int nbase) {
  __shared__ __align__(16) u16 LDSU16[65536];  // 128KB: 2 bufs x (A 32KB | B 32KB)

  int tid = threadIdx.x;
  int wave = tid >> 6, lane = tid & 63, quad = lane >> 4, l15 = lane & 15;
  int wr = wave >> 2, wc = wave & 3;  // 2M x 4N wave grid

  // XCD-chunked bijective remap (nwg = 384 or 128, both %8==0), m-fastest.
  int nwg = gridDim.x * gridDim.y;
  int orig = blockIdx.y * gridDim.x + blockIdx.x;
  int id = (orig & 7) * (nwg >> 3) + (orig >> 3);
  int mb = id & 31, nb = id >> 5;  // gridDim.y = 32 always
  int m0 = mb * 256;
  int bx = nb + nbase;
  int mode = bx >> 2;
  int n0g = bx * 256;
  const float* bias = (mode == 0) ? bq : (mode == 1) ? bk : (mode == 2) ? bv : bo;

  const u16* Ab = ((mode == 3) ? CTX : Xb) + (size_t)m0 * DD;
  const u16* Bb = WT + (size_t)n0g * DD;

  // staging source: wave w, lane l covers row u*64 + w*8 + (l>>3) of the tile,
  // source 16B chunk = (l&7) ^ (row&7); row&7 == (l>>3) since u*64+w*8 % 8 == 0.
  int srow = wave * 8 + (lane >> 3);
  int schunk = (lane & 7) ^ ((lane >> 3) & 7);
  const u16* srcA = Ab + (size_t)srow * DD + schunk * 8;
  const u16* srcB = Bb + (size_t)srow * DD + schunk * 8;

#define ISS_A(u, kk, bs) gl_lds16(srcA + (size_t)(u) * 64 * DD + (kk), \
                                  &LDSU16[(bs) * 32768 + (u) * 4096 + wave * 512])
#define ISS_B(u, kk, bs) gl_lds16(srcB + (size_t)(u) * 64 * DD + (kk), \
                                  &LDSU16[(bs) * 32768 + 16384 + (u) * 4096 + wave * 512])

  // fragment read offsets (u16 elements). logical chunk (ks*4+quad) ^ (l15&7).
  int swz = l15 & 7;
  int c0 = (quad ^ swz) * 8, c1 = ((4 + quad) ^ swz) * 8;
  int aoff0 = (wr * 128 + l15) * 64 + c0;
  int aoff1 = (wr * 128 + l15) * 64 + c1;
  int boff0 = (wc * 64 + l15) * 64 + c0;
  int boff1 = (wc * 64 + l15) * 64 + c1;

  v8s aR[4][2], bR[4][2];
  v4f acc[8][4] = {};

  // prologue: stage tile 0 (ages: A0,A2,B0..B3 oldest; A1,A3 may stay in flight)
  ISS_A(0, 0, 0); ISS_A(2, 0, 0);
  ISS_B(0, 0, 0); ISS_B(1, 0, 0); ISS_B(2, 0, 0); ISS_B(3, 0, 0);
  ISS_A(1, 0, 0); ISS_A(3, 0, 0);
  VMCNT(2);
  SBAR();

#pragma unroll 1
  for (int t = 0; t < 16; ++t) {
    int cur = t & 1, nxt = cur ^ 1;
    int kn = (t + 1) * 64;
    const u16* LA = &LDSU16[cur * 32768];
    const u16* LB = LA + 16384;

    // ---- P1: read a-lo + b[0,1]; issue next A0,A2; MFMA m0-3 x n0-1 ----
#pragma unroll
    for (int i = 0; i < 4; ++i) {
      aR[i][0] = *(const v8s*)&LA[aoff0 + i * 1024];
      aR[i][1] = *(const v8s*)&LA[aoff1 + i * 1024];
    }
#pragma unroll
    for (int j = 0; j < 2; ++j) {
      bR[j][0] = *(const v8s*)&LB[boff0 + j * 1024];
      bR[j][1] = *(const v8s*)&LB[boff1 + j * 1024];
    }
    if (t < 15) { ISS_A(0, kn, nxt); ISS_A(2, kn, nxt); }
    SBAR();
    __builtin_amdgcn_s_setprio(1);
#pragma unroll
    for (int i = 0; i < 4; ++i)
#pragma unroll
      for (int j = 0; j < 2; ++j) {
        acc[i][j] = MFMA16(aR[i][0], bR[j][0], acc[i][j]);
        acc[i][j] = MFMA16(aR[i][1], bR[j][1], acc[i][j]);
      }
    __builtin_amdgcn_s_setprio(0);
    SBAR();

    // ---- P2: read b[2,3]; issue next B0,B1; MFMA m0-3 x n2-3; vmcnt(4) ----
#pragma unroll
    for (int j = 0; j < 2; ++j) {
      bR[2 + j][0] = *(const v8s*)&LB[boff0 + (2 + j) * 1024];
      bR[2 + j][1] = *(const v8s*)&LB[boff1 + (2 + j) * 1024];
    }
    if (t < 15) { ISS_B(0, kn, nxt); ISS_B(1, kn, nxt); }
    SBAR();
    __builtin_amdgcn_s_setprio(1);
#pragma unroll
    for (int i = 0; i < 4; ++i)
#pragma unroll
      for (int j = 0; j < 2; ++j) {
        acc[i][2 + j] = MFMA16(aR[i][0], bR[2 + j][0], acc[i][2 + j]);
        acc[i][2 + j] = MFMA16(aR[i][1], bR[2 + j][1], acc[i][2 + j]);
      }
    __builtin_amdgcn_s_setprio(0);
    if (t < 15) { VMCNT(4); } else { VMCNT(0); }  // cur A1,A3 landed for P3
    SBAR();

    // ---- P3: read a-hi; issue next B2,B3; MFMA m4-7 x n2-3 ----
#pragma unroll
    for (int i = 0; i < 4; ++i) {
      aR[i][0] = *(const v8s*)&LA[aoff0 + (4 + i) * 1024];
      aR[i][1] = *(const v8s*)&LA[aoff1 + (4 + i) * 1024];
    }
    if (t < 15) { ISS_B(2, kn, nxt); ISS_B(3, kn, nxt); }
    SBAR();
    __builtin_amdgcn_s_setprio(1);
#pragma unroll
    for (int i = 0; i < 4; ++i)
#pragma unroll
      for (int j = 0; j < 2; ++j) {
        acc[4 + i][2 + j] = MFMA16(aR[i][0], bR[2 + j][0], acc[4 + i][2 + j]);
        acc[4 + i][2 + j] = MFMA16(aR[i][1], bR[2 + j][1], acc[4 + i][2 + j]);
      }
    __builtin_amdgcn_s_setprio(0);
    SBAR();

    // ---- P4: issue next A1,A3; MFMA m4-7 x n0-1; vmcnt(2) ----
    if (t < 15) { ISS_A(1, kn, nxt); ISS_A(3, kn, nxt); }
    SBAR();
    __builtin_amdgcn_s_setprio(1);
#pragma unroll
    for (int i = 0; i < 4; ++i)
#pragma unroll
      for (int j = 0; j < 2; ++j) {
        acc[4 + i][j] = MFMA16(aR[i][0], bR[j][0], acc[4 + i][j]);
        acc[4 + i][j] = MFMA16(aR[i][1], bR[j][1], acc[4 + i][j]);
      }
    __builtin_amdgcn_s_setprio(0);
    if (t < 15) { VMCNT(2); }  // next tile's A0,A2,B0..B3 landed for its P1
    SBAR();
  }
#undef ISS_A
#undef ISS_B

  // ---- epilogue: per-wave C-tile (16KB) staged in dead K-loop LDS ----
  int nbcol = (n0g + wc * 64) & (DD - 1);  // 64-aligned -> one head for Q/K/V
  u16* ct = &LDSU16[wave * 8192];
  int mbase = m0 + wr * 128;

  if (mode == 2) {
    // ct[d(64)][l(128)]; Vt[b,h,d,l]
#pragma unroll
    for (int nf = 0; nf < 4; ++nf) {
      int np = nf * 16 + l15;
      float bias_v = bias[(nbcol + np) & (DD - 1)];
#pragma unroll
      for (int mf = 0; mf < 8; ++mf) {
        ushort4 p;
        p.x = f2bf(acc[mf][nf][0] + bias_v);
        p.y = f2bf(acc[mf][nf][1] + bias_v);
        p.z = f2bf(acc[mf][nf][2] + bias_v);
        p.w = f2bf(acc[mf][nf][3] + bias_v);
        *(ushort4*)&ct[np * 128 + mf * 16 + quad * 4] = p;
      }
    }
    int b = mbase >> 11, lb = mbase & (LL - 1);
#pragma unroll
    for (int g = 0; g < 16; ++g) {
      int np = g * 4 + quad;
      int n = (nbcol + np) & (DD - 1);
      int h = n >> 6, d = n & 63;
      v8s v = *(const v8s*)&ct[np * 128 + l15 * 8];
      *(v8s*)&Vtb[((size_t)(b * NH + h) * HD + d) * LL + lb + l15 * 8] = v;
    }
  } else {
    // ct[m(128)][n(64)]; row-major stores
#pragma unroll
    for (int nf = 0; nf < 4; ++nf) {
      int np = nf * 16 + l15;
      float bias_v = bias[(nbcol + np) & (DD - 1)];
#pragma unroll
      for (int mf = 0; mf < 8; ++mf)
#pragma unroll
        for (int r = 0; r < 4; ++r) {
          float v = acc[mf][nf][r] + bias_v;
          if (mode == 0) v *= QSCALE;
          ct[(mf * 16 + quad * 4 + r) * 64 + np] = f2bf(v);
        }
    }
    int rn = lane >> 3, rk = lane & 7;
    int h = nbcol >> 6;
    u16* qk = (mode == 0) ? Qb : Kb;
#pragma unroll
    for (int g = 0; g < 16; ++g) {
      int row = g * 8 + rn;
      int m_g = mbase + row;
      v8s v = *(const v8s*)&ct[row * 64 + rk * 8];
      if (mode == 3) {
        *(v8s*)&projb[(size_t)m_g * DD + nbcol + rk * 8] = v;
      } else {
        int b = m_g >> 11, l = m_g & (LL - 1);
        *(v8s*)&qk[((size_t)(b * NH + h) * LL + l) * HD + rk * 8] = v;
      }
    }
  }
}

// ---------------- flash attention, fixed-max softmax, in-register P --------------
__global__ __launch_bounds__(256, 4) void attn(
    const u16* __restrict__ Qb, const u16* __restrict__ Kb,
    const u16* __restrict__ Vtb, u16* __restrict__ ctx) {
  __shared__ __align__(16) u16 Ks[64 * PAD];       // [key][d]
  __shared__ __align__(16) u16 Vs[64 * PAD];       // [d][key]

  int tid = threadIdx.x;
  int wave = tid >> 6, lane = tid & 63, quad = lane >> 4, l15 = lane & 15;

  int orig = blockIdx.y * gridDim.x + blockIdx.x;
  int cpx = (gridDim.x * gridDim.y) >> 3;
  int id = (orig & 7) * cpx + (orig >> 3);
  int q0 = (id & (gridDim.x - 1)) * 128;  // gridDim.x = 16 (pow2)
  int bh = id / gridDim.x;

  v8s aq[2][2];
#pragma unroll
  for (int s2 = 0; s2 < 2; ++s2) {
    const u16* Qp = Qb + ((size_t)bh * LL + q0 + s2 * 64 + wave * 16 + l15) * HD;
    aq[s2][0] = *(const v8s*)(Qp + quad * 8);
    aq[s2][1] = *(const v8s*)(Qp + 32 + quad * 8);
  }

  v4f o[2][4] = {};
  float ls2[2] = {0.f, 0.f};

  const u16* Kbase = Kb + (size_t)bh * LL * HD;
  const u16* Vbase = Vtb + (size_t)bh * HD * LL;

  for (int kt = 0; kt < LL / 64; ++kt) {
    int k0 = kt * 64;
    __syncthreads();
#pragma unroll
    for (int i = 0; i < 2; ++i) {
      int cid = i * 256 + tid;
      int r = cid >> 3, c = (cid & 7) * 8;
      *(v8s*)&Ks[r * PAD + c] = *(const v8s*)(Kbase + (size_t)(k0 + r) * HD + c);
      *(v8s*)&Vs[r * PAD + c] = *(const v8s*)(Vbase + (size_t)r * LL + k0 + c);
    }
    __syncthreads();

    v8s ak[4][2];
#pragma unroll
    for (int t = 0; t < 4; ++t) {
      ak[t][0] = *(const v8s*)&Ks[(t * 16 + l15) * PAD + quad * 8];
      ak[t][1] = *(const v8s*)&Ks[(t * 16 + l15) * PAD + 32 + quad * 8];
    }

    v8s ap[2][2];
#pragma unroll
    for (int s2 = 0; s2 < 2; ++s2) {
      v4f s[4];
#pragma unroll
      for (int t = 0; t < 4; ++t) {
        v4f z = {};
        z = __builtin_amdgcn_mfma_f32_16x16x32_bf16(ak[t][0], aq[s2][0], z, 0, 0, 0);
        s[t] = __builtin_amdgcn_mfma_f32_16x16x32_bf16(ak[t][1], aq[s2][1], z, 0, 0, 0);
      }
      unsigned W[4][2];
      float psum = 0.f;
#pragma unroll
      for (int t = 0; t < 4; ++t) {
        float p0 = __builtin_amdgcn_exp2f(s[t][0] - 64.f);
        float p1 = __builtin_amdgcn_exp2f(s[t][1] - 64.f);
        float p2 = __builtin_amdgcn_exp2f(s[t][2] - 64.f);
        float p3 = __builtin_amdgcn_exp2f(s[t][3] - 64.f);
        psum += (p0 + p1) + (p2 + p3);
        W[t][0] = cvtpk_bf16(p0, p1);
        W[t][1] = cvtpk_bf16(p2, p3);
      }
      ls2[s2] += psum;
      union { v4u u; v8s s8; } cc0, cc1;
#pragma unroll
      for (int j = 0; j < 2; ++j) {
        unsigned a = W[0][j], b = W[1][j];
        pl32swap(a, b); pl16swap(a, b);
        cc0.u[j] = a; cc0.u[2 + j] = b;
        unsigned a2 = W[2][j], b2 = W[3][j];
        pl32swap(a2, b2); pl16swap(a2, b2);
        cc1.u[j] = a2; cc1.u[2 + j] = b2;
      }
      ap[s2][0] = cc0.s8; ap[s2][1] = cc1.s8;
    }

#pragma unroll
    for (int t = 0; t < 4; ++t) {
      v8s vb0 = *(const v8s*)&Vs[(t * 16 + l15) * PAD + quad * 8];
      v8s vb1 = *(const v8s*)&Vs[(t * 16 + l15) * PAD + 32 + quad * 8];
#pragma unroll
      for (int s2 = 0; s2 < 2; ++s2) {
        o[s2][t] = __builtin_amdgcn_mfma_f32_16x16x32_bf16(ap[s2][0], vb0, o[s2][t], 0, 0, 0);
        o[s2][t] = __builtin_amdgcn_mfma_f32_16x16x32_bf16(ap[s2][1], vb1, o[s2][t], 0, 0, 0);
      }
    }
  }

  int b = bh >> 4, h = bh & 15;
#pragma unroll
  for (int s2 = 0; s2 < 2; ++s2) {
    float tot = ls2[s2];
    tot += __shfl_xor(tot, 16);
    tot += __shfl_xor(tot, 32);
    float recip = 1.f / tot;
#pragma unroll
    for (int r = 0; r < 4; ++r) {
      float inv = __shfl(recip, quad * 4 + r);
      int l = q0 + s2 * 64 + wave * 16 + quad * 4 + r;
#pragma unroll
      for (int t = 0; t < 4; ++t)
        ctx[((size_t)(b * LL + l)) * DD + h * HD + t * 16 + l15] =
            f2bf(o[s2][t][r] * inv);
    }
  }
}

// ---------------- residual + LayerNorm -> fp32 output ----------------------------
__global__ __launch_bounds__(256) void resid_ln(
    const float* __restrict__ x, const u16* __restrict__ projb,
    const float* __restrict__ gamma, const float* __restrict__ beta,
    float* __restrict__ out) {
  int row = blockIdx.x, tid = threadIdx.x;
  int base = tid * 4;
  float4 xv = *(const float4*)(x + (size_t)row * DD + base);
  ushort4 pv = *(const ushort4*)(projb + (size_t)row * DD + base);
  float y0 = xv.x + bf2f(pv.x), y1 = xv.y + bf2f(pv.y);
  float y2 = xv.z + bf2f(pv.z), y3 = xv.w + bf2f(pv.w);

  float s = y0 + y1 + y2 + y3;
  s += __shfl_xor(s, 1);  s += __shfl_xor(s, 2);  s += __shfl_xor(s, 4);
  s += __shfl_xor(s, 8);  s += __shfl_xor(s, 16); s += __shfl_xor(s, 32);
  __shared__ float red[8];
  int wv = tid >> 6, ln = tid & 63;
  if (ln == 0) red[wv] = s;
  __syncthreads();
  float mu = (red[0] + red[1] + red[2] + red[3]) * (1.f / DD);

  float d0 = y0 - mu, d1 = y1 - mu, d2 = y2 - mu, d3 = y3 - mu;
  float vv = d0 * d0 + d1 * d1 + d2 * d2 + d3 * d3;
  vv += __shfl_xor(vv, 1);  vv += __shfl_xor(vv, 2);  vv += __shfl_xor(vv, 4);
  vv += __shfl_xor(vv, 8);  vv += __shfl_xor(vv, 16); vv += __shfl_xor(vv, 32);
  if (ln == 0) red[4 + wv] = vv;
  __syncthreads();
  float var = (red[4] + red[5] + red[6] + red[7]) * (1.f / DD);
  float rstd = rsqrtf(var + 1e-5f);

  float4 gv = *(const float4*)(gamma + base);
  float4 bv = *(const float4*)(beta + base);
  float4 ov;
  ov.x = d0 * rstd * gv.x + bv.x;
  ov.y = d1 * rstd * gv.y + bv.y;
  ov.z = d2 * rstd * gv.z + bv.z;
  ov.w = d3 * rstd * gv.w + bv.w;
  *(float4*)(out + (size_t)row * DD + base) = ov;
}

extern "C" void kernel_launch(void* const* d_in, const int* in_sizes, int n_in,
                              void* d_out, int out_size, void* d_ws, size_t ws_size,
                              hipStream_t stream) {
  (void)ws_size;
  float* out = (float*)d_out;

  bool ok = (n_in == 11) && (out_size == BB * LL * DD);
  if (ok) {
    const int want[11] = {BB * LL * DD, DD * DD, DD, DD * DD, DD, DD * DD,
                          DD, DD * DD, DD, DD, DD};
    for (int i = 0; i < 11; ++i) ok = ok && (in_sizes[i] == want[i]);
  }
  if (!ok) {
    fill_val<<<(out_size + 255) / 256, 256, 0, stream>>>(out, 1000.0f, out_size);
    return;
  }

  const float* x     = (const float*)d_in[0];
  const float* Wq    = (const float*)d_in[1];
  const float* bq    = (const float*)d_in[2];
  const float* Wk    = (const float*)d_in[3];
  const float* bk    = (const float*)d_in[4];
  const float* Wv    = (const float*)d_in[5];
  const float* bv    = (const float*)d_in[6];
  const float* Wo    = (const float*)d_in[7];
  const float* bo    = (const float*)d_in[8];
  const float* gamma = (const float*)d_in[9];
  const float* beta  = (const float*)d_in[10];

  // ws: WT 8MB | Xb 16 | Qb 16 | Kb 16 | Vtb 16  (72MB)
  char* ws = (char*)d_ws;
  u16* WT   = (u16*)(ws);
  u16* Xb   = (u16*)(ws + (size_t)8 * 1024 * 1024);
  u16* Qb   = (u16*)(ws + (size_t)24 * 1024 * 1024);
  u16* Kb   = (u16*)(ws + (size_t)40 * 1024 * 1024);
  u16* Vtb  = (u16*)(ws + (size_t)56 * 1024 * 1024);
  u16* ctxO = (u16*)d_out;
  u16* projb = Xb;  // Xb dead after QKV GEMM

  cast_x<<<4096, 256, 0, stream>>>(x, Xb);
  transpose_w<<<dim3(16, 16, 4), 256, 0, stream>>>(Wq, Wk, Wv, Wo, WT);
  // fused QKV: N=3072 (12 n-blocks of 256), M=8192 (32 m-blocks of 256)
  gemm256<<<dim3(12, 32), 512, 0, stream>>>(Xb, ctxO, WT, bq, bk, bv, bo,
                                            Qb, Kb, Vtb, projb, 0);
  attn<<<dim3(LL / 128, BB * NH), 256, 0, stream>>>(Qb, Kb, Vtb, ctxO);
  // O-proj: mode 3 (nbase 12), N=1024 (4 n-blocks)
  gemm256<<<dim3(4, 32), 512, 0, stream>>>(Xb, ctxO, WT, bq, bk, bv, bo,
                                           Qb, Kb, Vtb, projb, 12);
  resid_ln<<<8192, 256, 0, stream>>>(x, projb, gamma, beta, out);
}